// Round 5
// baseline (2165.333 us; speedup 1.0000x reference)
//
#include <hip/hip_runtime.h>
#include <hip/hip_bf16.h>

#define R_TOT 8192
#define NX 32
#define NM 64
#define STRD 33
#define VSTRD 36
#define OPSTRD 36
#define WARM 12
#define CHUNKF 4
#define CHUNKB 8

// permuted row index within a stored column: slot of row r is PIDX(r)
#define PIDX(k) ((((k) & 1) << 4) | ((k) >> 1))

// single-wave "barrier": lockstep wave64 + drain LDS ops. Valid only for 64-thread blocks.
__device__ inline void wsync() { asm volatile("s_waitcnt lgkmcnt(0)" ::: "memory"); }

// wave-uniform broadcast of lane l's value (l compile-time)
__device__ inline float rdlane(float v, int l) {
  return __uint_as_float(__builtin_amdgcn_readlane(__float_as_uint(v), l));
}

// ---- bf16 bit helpers (RNE) ----
__device__ inline unsigned f2bf(float x) {
  unsigned u = __float_as_uint(x);
  return (u + 0x7fffu + ((u >> 16) & 1u)) >> 16;
}

// ---- 16-element vector store/load (float or bf16 storage) ----
__device__ inline void st16(float* g, const float* v) {
  float4* p = reinterpret_cast<float4*>(g);
  p[0] = make_float4(v[0], v[1], v[2], v[3]);
  p[1] = make_float4(v[4], v[5], v[6], v[7]);
  p[2] = make_float4(v[8], v[9], v[10], v[11]);
  p[3] = make_float4(v[12], v[13], v[14], v[15]);
}
__device__ inline void st16(__hip_bfloat16* g, const float* v) {
  unsigned w[8];
  #pragma unroll
  for (int q = 0; q < 8; ++q)
    w[q] = (f2bf(v[2*q+1]) << 16) | f2bf(v[2*q]);
  uint4* p = reinterpret_cast<uint4*>(g);
  p[0] = make_uint4(w[0], w[1], w[2], w[3]);
  p[1] = make_uint4(w[4], w[5], w[6], w[7]);
}
__device__ inline void ld16(float* v, const float* g) {
  const float4* p = reinterpret_cast<const float4*>(g);
  float4 a = p[0], b = p[1], c = p[2], d = p[3];
  v[0]=a.x; v[1]=a.y; v[2]=a.z; v[3]=a.w;
  v[4]=b.x; v[5]=b.y; v[6]=b.z; v[7]=b.w;
  v[8]=c.x; v[9]=c.y; v[10]=c.z; v[11]=c.w;
  v[12]=d.x; v[13]=d.y; v[14]=d.z; v[15]=d.w;
}
__device__ inline void ld16(float* v, const __hip_bfloat16* g) {
  const uint4* p = reinterpret_cast<const uint4*>(g);
  uint4 a = p[0], b = p[1];
  unsigned w[8] = {a.x, a.y, a.z, a.w, b.x, b.y, b.z, b.w};
  #pragma unroll
  for (int q = 0; q < 8; ++q) {
    v[2*q]   = __uint_as_float(w[q] << 16);
    v[2*q+1] = __uint_as_float(w[q] & 0xffff0000u);
  }
}

// ---------------- precompute ap = A@P, apat = ap@A^T (shared by all chunks) --------------
__global__ __launch_bounds__(64) void precomp_kernel(
    const float* __restrict__ A, const float* __restrict__ P,
    float* __restrict__ apG, float* __restrict__ apatG)
{
  __shared__ float As[NX*STRD], Ps[NX*STRD], aps[NX*STRD];
  const int t = threadIdx.x;
  for (int e = t; e < NX*NX; e += 64) {
    int i = e >> 5, j = e & 31;
    As[i*STRD+j] = A[e];
    Ps[i*STRD+j] = P[e];
  }
  wsync();
  for (int e = t; e < NX*NX; e += 64) {
    int i = e >> 5, j = e & 31;
    float s = 0.f;
    for (int k = 0; k < NX; ++k) s += As[i*STRD+k] * Ps[k*STRD+j];
    aps[i*STRD+j] = s;
    apG[e] = s;
  }
  wsync();
  for (int e = t; e < NX*NX; e += 64) {
    int i = e >> 5, j = e & 31;
    float s = 0.f;
    for (int k = 0; k < NX; ++k) s += aps[i*STRD+k] * As[j*STRD+k];
    apatG[e] = s;
  }
}

// ---------------- forward: chunked Riccati scan ----------------
// one wave per chunk. Matmul phases: lane owns (i = half+2m, j = lane), m=0..15.
// LDL/zeta in registers (lane r = t&31 owns row r; readlane broadcasts).
// Global layouts (consumed by bwd):
//   xOut:  column-major per r:  x[r][c*32 + i]        = xi[i][c]   (lane c stores 32 contig)
//   offOut: permuted col-major: off[r][c*32 + PIDX(i)] = off[i][c] (thread stores 16 contig)
// LDS: smx serves S-matrix (S-phase->row-load) then xi (zeta->off-phase) — disjoint lifetimes.
// offP[k*OPSTRD + PIDX(i)] = off[i][k]: read by u-phase (prev step), pred-phase; b128 rows.
template<typename ST>
__global__ __launch_bounds__(64, 2) void fwd_kernel(
    const float* __restrict__ hessAll, const float* __restrict__ gradAll,
    const float* __restrict__ apG, const float* __restrict__ apatG,
    const float* __restrict__ P, const float* __restrict__ initP,
    ST* __restrict__ offOut, ST* __restrict__ xOut, float* __restrict__ uOut)
{
  __shared__ float apP[NX*32], smx[NX*STRD], offP[NX*OPSTRD];
  __shared__ float uv[NX], tv[NX];
  const int t = threadIdx.x;
  const int lane = t & 31, half = t >> 5;
  const int pl = PIDX(lane);
  const int c = blockIdx.x;
  const int r0 = c * CHUNKF, r1 = r0 + CHUNKF;

  float PsR[16], apatR[16], predR[16], hessR[16];
  float gradR;

  const int cl = 16*(lane & 1) + (lane >> 1);   // permuted-column map
  #pragma unroll
  for (int m = 0; m < 16; ++m) {
    int e = t + 64*m;
    apP[(half + 2*m)*32 + cl] = apG[e];
    PsR[m]   = P[e];
    apatR[m] = apatG[e];
  }
  for (int e = t; e < NX*OPSTRD; e += 64) offP[e] = 0.f;
  wsync();

  int rstart = r0 - WARM;
  if (rstart < 0) rstart = 0;
  const bool exact = (rstart == 0);

  #pragma unroll
  for (int m = 0; m < 16; ++m)
    predR[m] = exact ? initP[t + 64*m] : PsR[m];   // any SPD init works (contraction)
  if (t < NX) uv[t] = 0.f;
  wsync();

  // preload first step's hess/grad
  {
    const float* hess = hessAll + (size_t)rstart * (NX*NX);
    #pragma unroll
    for (int m = 0; m < 16; ++m) hessR[m] = hess[t + 64*m];
    gradR = gradAll[(size_t)rstart * NX + lane];
  }

  for (int r = rstart; r < r1; ++r) {
    const bool last = (r == R_TOT-1);
    // ---- S = pred + hess (+ apat) into smx ----
    #pragma unroll
    for (int m = 0; m < 16; ++m) {
      float v = predR[m] + hessR[m];
      if (!last) v += apatR[m];
      smx[(half + 2*m)*STRD + lane] = v;
    }
    wsync();
    // prefetch next step's hess (latency hidden under LDL/zeta)
    if (r + 1 < r1) {
      const float* hn = hessAll + (size_t)(r+1) * (NX*NX);
      #pragma unroll
      for (int m = 0; m < 16; ++m) hessR[m] = hn[t + 64*m];
    }
    // ---- row-load: lane r = t&31 takes row r (upper half mirrors) ----
    float row[NX];
    #pragma unroll
    for (int k = 0; k < NX; ++k) row[k] = smx[lane*STRD + k];
    // ---- LDL^T in registers, right-looking, unscaled columns: row[c] = l~_rc * d_c ----
    #pragma unroll
    for (int j = 0; j < NX-1; ++j) {
      float invd = __builtin_amdgcn_rcpf(rdlane(row[j], j));
      float f = (lane > j) ? row[j] * invd : 0.f;
      #pragma unroll
      for (int cc = j+1; cc < NX; ++cc)
        row[cc] = fmaf(-f, rdlane(row[cc], j), row[cc]);
    }
    // ---- zeta = D^{-1} L~^{-1} (column `lane` per lane); zcs = chol^{-1} column ----
    float zcs[NX];
    {
      float zc[NX];
      #pragma unroll
      for (int i = 0; i < NX; ++i) {
        float d_i = rdlane(row[i], i);
        float di = __builtin_amdgcn_rcpf(d_i);
        float s = 0.f;
        #pragma unroll
        for (int k = 0; k < i; ++k) s = fmaf(rdlane(row[k], i), zc[k], s);
        zc[i] = (i == lane) ? di : -di * s;
        zcs[i] = zc[i] * __builtin_amdgcn_sqrtf(d_i);
      }
    }
    if (t < NX) {
      #pragma unroll
      for (int i = 0; i < NX; ++i) smx[i*STRD + t] = zcs[i];   // xi into LDS (transpose)
      if (r >= r0) {
        ST* xp = xOut + (size_t)r * (NX*NX) + t*NX;
        st16(xp, zcs);
        st16(xp + 16, zcs + 16);
      }
    }
    wsync();
    // ---- u update: tv = grad - u_prev @ off_prev^T ; u_new = tv @ xi^T ----
    if (t < NX) {
      float s = gradR;
      #pragma unroll 4
      for (int m = 0; m < NX; ++m) s -= uv[m] * offP[m*OPSTRD + pl];   // off_prev[t][m]
      tv[t] = s;
    }
    wsync();
    float unew = 0.f;
    if (t < NX) {
      float s = 0.f;
      #pragma unroll 4
      for (int k = 0; k < NX; ++k) s += tv[k] * smx[t*STRD+k];
      unew = s;
    }
    wsync();
    if (t < NX) {
      uv[t] = unew;
      if (r >= r0) uOut[(size_t)r*NX + t] = unew;
    }
    if (r + 1 < r1) gradR = gradAll[(size_t)(r+1) * NX + lane];
    wsync();   // uv visible; offP reads (u phase) drained before overwrite below
    // ---- off[jj][ii] = -sum_k xi[ii][k] ap[k][jj]; ii = lane, jj = half+2m ----
    {
      float negR[16];
      {
        float offR[16];
        #pragma unroll
        for (int m = 0; m < 16; ++m) offR[m] = 0.f;
        #pragma unroll
        for (int k = 0; k < NX; ++k) {
          float xv = smx[lane*STRD + k];           // xi row `lane`, conflict-free
          const float4* apv = reinterpret_cast<const float4*>(&apP[k*32 + 16*half]);
          float4 a0 = apv[0], a1 = apv[1], a2 = apv[2], a3 = apv[3];   // broadcast b128
          offR[0]  += xv * a0.x; offR[1]  += xv * a0.y; offR[2]  += xv * a0.z; offR[3]  += xv * a0.w;
          offR[4]  += xv * a1.x; offR[5]  += xv * a1.y; offR[6]  += xv * a1.z; offR[7]  += xv * a1.w;
          offR[8]  += xv * a2.x; offR[9]  += xv * a2.y; offR[10] += xv * a2.z; offR[11] += xv * a2.w;
          offR[12] += xv * a3.x; offR[13] += xv * a3.y; offR[14] += xv * a3.z; offR[15] += xv * a3.w;
        }
        #pragma unroll
        for (int m = 0; m < 16; ++m) negR[m] = -offR[m];
      }
      // offP[k=lane][16*half + m] = off[half+2m][lane]
      float4* opw = reinterpret_cast<float4*>(&offP[lane*OPSTRD + 16*half]);
      opw[0] = make_float4(negR[0],  negR[1],  negR[2],  negR[3]);
      opw[1] = make_float4(negR[4],  negR[5],  negR[6],  negR[7]);
      opw[2] = make_float4(negR[8],  negR[9],  negR[10], negR[11]);
      opw[3] = make_float4(negR[12], negR[13], negR[14], negR[15]);
      if (r >= r0)
        st16(offOut + (size_t)r * (NX*NX) + lane*NX + 16*half, negR);
    }
    wsync();
    // ---- pred = P - off @ off^T (into registers) ----
    #pragma unroll
    for (int m = 0; m < 16; ++m) predR[m] = PsR[m];
    #pragma unroll
    for (int k = 0; k < NX; ++k) {
      float fj = offP[k*OPSTRD + pl];              // off[lane][k], conflict-free
      const float4* ov = reinterpret_cast<const float4*>(&offP[k*OPSTRD + 16*half]);
      float4 o0 = ov[0], o1 = ov[1], o2 = ov[2], o3 = ov[3];   // broadcast b128
      predR[0]  -= o0.x*fj; predR[1]  -= o0.y*fj; predR[2]  -= o0.z*fj; predR[3]  -= o0.w*fj;
      predR[4]  -= o1.x*fj; predR[5]  -= o1.y*fj; predR[6]  -= o1.z*fj; predR[7]  -= o1.w*fj;
      predR[8]  -= o2.x*fj; predR[9]  -= o2.y*fj; predR[10] -= o2.z*fj; predR[11] -= o2.w*fj;
      predR[12] -= o3.x*fj; predR[13] -= o3.y*fj; predR[14] -= o3.z*fj; predR[15] -= o3.w*fj;
    }
    wsync();
  }
}

// ---------------- backward: chunked reverse linear scan ----------------
// 256 threads/chunk. Thread owns rows i = grp+8m (grp = t>>5), col j = t&31.
// off/xi columns loaded straight from global into registers (vector loads,
// compile-time un-permute) — no LDS staging, 2 barriers/step.
template<typename ST>
__global__ __launch_bounds__(256, 4) void bwd_kernel(
    const ST* __restrict__ offIn, const ST* __restrict__ xIn, const float* __restrict__ uIn,
    const float* __restrict__ epsx, float* __restrict__ outp)
{
  __shared__ float vw[(NM+1)*VSTRD], bb[(NM+1)*VSTRD];
  const int t = threadIdx.x;
  const int lane = t & 31, grp = t >> 5;
  const int c = blockIdx.x;
  const int r0 = c * CHUNKB, r1 = r0 + CHUNKB;
  int rstart = r1 + WARM; if (rstart > R_TOT) rstart = R_TOT;
  const bool has64 = (grp == 0);

  for (int e = t; e < (NM+1)*VSTRD; e += 256) vw[e] = 0.f;

  float gR[9];
  {
    int r = rstart - 1;
    const float* eps_r = epsx + (size_t)r * (NM*NX);
    const float* u_r   = uIn + (size_t)r * NX;
    #pragma unroll
    for (int m = 0; m < 8; ++m) {
      int i = grp + 8*m;
      gR[m] = (i == 0) ? u_r[lane] : eps_r[(i-1)*NX + lane];
    }
    gR[8] = has64 ? eps_r[63*NX + lane] : 0.f;
  }
  __syncthreads();

  for (int r = rstart - 1; r >= r0; --r) {
    const size_t base = (size_t)r * (NX*NX);
    // ---- load off column `lane` (permuted storage) into regs ----
    float fot[NX];
    ld16(fot,      offIn + base + lane*NX);
    ld16(fot + 16, offIn + base + lane*NX + 16);
    float acc[9];
    #pragma unroll
    for (int m = 0; m < 9; ++m) acc[m] = gR[m];
    // ---- bb = g - vw @ off ; off[k][lane] = fot[PIDX(k)] ----
    #pragma unroll
    for (int m = 0; m < 8; ++m) {
      const float4* vr = reinterpret_cast<const float4*>(&vw[(grp + 8*m)*VSTRD]);
      #pragma unroll
      for (int q = 0; q < 8; ++q) {
        float4 v4 = vr[q];                        // broadcast b128
        acc[m] -= v4.x*fot[PIDX(4*q)] + v4.y*fot[PIDX(4*q+1)]
                + v4.z*fot[PIDX(4*q+2)] + v4.w*fot[PIDX(4*q+3)];
      }
    }
    if (has64) {
      const float4* vr = reinterpret_cast<const float4*>(&vw[64*VSTRD]);
      #pragma unroll
      for (int q = 0; q < 8; ++q) {
        float4 v4 = vr[q];
        acc[8] -= v4.x*fot[PIDX(4*q)] + v4.y*fot[PIDX(4*q+1)]
                + v4.z*fot[PIDX(4*q+2)] + v4.w*fot[PIDX(4*q+3)];
      }
    }
    // ---- issue xi column load (latency hides under barrier) ----
    float fxt[NX];
    ld16(fxt,      xIn + base + lane*NX);
    ld16(fxt + 16, xIn + base + lane*NX + 16);
    #pragma unroll
    for (int m = 0; m < 8; ++m) bb[(grp + 8*m)*VSTRD + lane] = acc[m];
    if (has64) bb[64*VSTRD + lane] = acc[8];
    // prefetch next (lower) step's g
    if (r > r0) {
      const float* eps_n = epsx + (size_t)(r-1) * (NM*NX);
      const float* u_n   = uIn + (size_t)(r-1) * NX;
      #pragma unroll
      for (int m = 0; m < 8; ++m) {
        int i = grp + 8*m;
        gR[m] = (i == 0) ? u_n[lane] : eps_n[(i-1)*NX + lane];
      }
      if (has64) gR[8] = eps_n[63*NX + lane];
    }
    __syncthreads();
    // ---- vw = bb @ xi ; xi[k][lane] = fxt[k] ----
    float vacc[9];
    #pragma unroll
    for (int m = 0; m < 9; ++m) vacc[m] = 0.f;
    #pragma unroll
    for (int m = 0; m < 8; ++m) {
      const float4* br = reinterpret_cast<const float4*>(&bb[(grp + 8*m)*VSTRD]);
      #pragma unroll
      for (int q = 0; q < 8; ++q) {
        float4 b4 = br[q];                        // broadcast b128
        vacc[m] += b4.x*fxt[4*q] + b4.y*fxt[4*q+1] + b4.z*fxt[4*q+2] + b4.w*fxt[4*q+3];
      }
    }
    if (has64) {
      const float4* br = reinterpret_cast<const float4*>(&bb[64*VSTRD]);
      #pragma unroll
      for (int q = 0; q < 8; ++q) {
        float4 b4 = br[q];
        vacc[8] += b4.x*fxt[4*q] + b4.y*fxt[4*q+1] + b4.z*fxt[4*q+2] + b4.w*fxt[4*q+3];
      }
    }
    #pragma unroll
    for (int m = 0; m < 8; ++m) vw[(grp + 8*m)*VSTRD + lane] = vacc[m];
    if (has64) vw[64*VSTRD + lane] = vacc[8];
    __syncthreads();
    // ---- out_r[i][j] = vw[i+1][j] + vw[0][j], rows i = grp+8m ----
    if (r < r1) {
      float v0 = vw[lane];
      float* out_r = outp + (size_t)r * (NM*NX);
      #pragma unroll
      for (int m = 0; m < 8; ++m)
        out_r[(grp + 8*m)*NX + lane] = vw[(grp + 8*m + 1)*VSTRD + lane] + v0;
    }
    // no trailing barrier: next vw write is fenced by next iteration's mid-step barrier
  }
}

extern "C" void kernel_launch(void* const* d_in, const int* in_sizes, int n_in,
                              void* d_out, int out_size, void* d_ws, size_t ws_size,
                              hipStream_t stream) {
  const float* hess  = (const float*)d_in[0];
  const float* grads = (const float*)d_in[1];
  const float* A     = (const float*)d_in[2];
  const float* P     = (const float*)d_in[3];
  const float* initP = (const float*)d_in[4];
  const float* epsx  = (const float*)d_in[5];
  float* outp = (float*)d_out;

  const size_t mats = (size_t)R_TOT * NX * NX;
  const size_t uN   = (size_t)R_TOT * NX;
  const size_t needF32 = 2ull * mats * sizeof(float) + uN * sizeof(float) + 2048 * sizeof(float);

  if (ws_size >= needF32) {
    float* offS  = (float*)d_ws;
    float* xS    = offS + mats;
    float* uS    = xS + mats;
    float* apG   = uS + uN;
    float* apatG = apG + 1024;
    precomp_kernel<<<dim3(1), dim3(64), 0, stream>>>(A, P, apG, apatG);
    fwd_kernel<float><<<dim3(R_TOT/CHUNKF), dim3(64), 0, stream>>>(
        hess, grads, apG, apatG, P, initP, offS, xS, uS);
    bwd_kernel<float><<<dim3(R_TOT/CHUNKB), dim3(256), 0, stream>>>(
        offS, xS, uS, epsx, outp);
  } else {
    __hip_bfloat16* offS = (__hip_bfloat16*)d_ws;
    __hip_bfloat16* xS   = offS + mats;
    float* uS            = (float*)(xS + mats);
    float* apG           = uS + uN;
    float* apatG         = apG + 1024;
    precomp_kernel<<<dim3(1), dim3(64), 0, stream>>>(A, P, apG, apatG);
    fwd_kernel<__hip_bfloat16><<<dim3(R_TOT/CHUNKF), dim3(64), 0, stream>>>(
        hess, grads, apG, apatG, P, initP, offS, xS, uS);
    bwd_kernel<__hip_bfloat16><<<dim3(R_TOT/CHUNKB), dim3(256), 0, stream>>>(
        offS, xS, uS, epsx, outp);
  }
}

// Round 6
// 563.361 us; speedup vs baseline: 3.8436x; 3.8436x over previous
//
#include <hip/hip_runtime.h>
#include <hip/hip_bf16.h>

#define R_TOT 8192
#define NX 32
#define NM 64
#define STRD 33
#define VSTRD 36
#define OPSTRD 36
#define WARM 12
#define CHUNKF 4
#define CHUNKB 16

// permuted row index within a stored column: slot of row r is PIDX(r)
#define PIDX(k) ((((k) & 1) << 4) | ((k) >> 1))

// single-wave "barrier": lockstep wave64 + drain LDS ops. Valid only for 64-thread blocks.
__device__ inline void wsync() { asm volatile("s_waitcnt lgkmcnt(0)" ::: "memory"); }

// wave-uniform broadcast of lane l's value (l compile-time)
__device__ inline float rdlane(float v, int l) {
  return __uint_as_float(__builtin_amdgcn_readlane(__float_as_uint(v), l));
}

// ---- bf16 bit helpers (RNE) ----
__device__ inline unsigned f2bf(float x) {
  unsigned u = __float_as_uint(x);
  return (u + 0x7fffu + ((u >> 16) & 1u)) >> 16;
}

// ---- 16-element vector store (float or bf16 storage) ----
__device__ inline void st16(float* g, const float* v) {
  float4* p = reinterpret_cast<float4*>(g);
  p[0] = make_float4(v[0], v[1], v[2], v[3]);
  p[1] = make_float4(v[4], v[5], v[6], v[7]);
  p[2] = make_float4(v[8], v[9], v[10], v[11]);
  p[3] = make_float4(v[12], v[13], v[14], v[15]);
}
__device__ inline void st16(__hip_bfloat16* g, const float* v) {
  unsigned w[8];
  #pragma unroll
  for (int q = 0; q < 8; ++q)
    w[q] = (f2bf(v[2*q+1]) << 16) | f2bf(v[2*q]);
  uint4* p = reinterpret_cast<uint4*>(g);
  p[0] = make_uint4(w[0], w[1], w[2], w[3]);
  p[1] = make_uint4(w[4], w[5], w[6], w[7]);
}

// ---- 4-element vector load (float or bf16 storage) ----
__device__ inline void ld4(float* v, const float* g) {
  float4 a = *reinterpret_cast<const float4*>(g);
  v[0] = a.x; v[1] = a.y; v[2] = a.z; v[3] = a.w;
}
__device__ inline void ld4(float* v, const __hip_bfloat16* g) {
  uint2 a = *reinterpret_cast<const uint2*>(g);
  v[0] = __uint_as_float(a.x << 16);
  v[1] = __uint_as_float(a.x & 0xffff0000u);
  v[2] = __uint_as_float(a.y << 16);
  v[3] = __uint_as_float(a.y & 0xffff0000u);
}

// ---------------- precompute ap = A@P, apat = ap@A^T (shared by all chunks) --------------
__global__ __launch_bounds__(64) void precomp_kernel(
    const float* __restrict__ A, const float* __restrict__ P,
    float* __restrict__ apG, float* __restrict__ apatG)
{
  __shared__ float As[NX*STRD], Ps[NX*STRD], aps[NX*STRD];
  const int t = threadIdx.x;
  for (int e = t; e < NX*NX; e += 64) {
    int i = e >> 5, j = e & 31;
    As[i*STRD+j] = A[e];
    Ps[i*STRD+j] = P[e];
  }
  wsync();
  for (int e = t; e < NX*NX; e += 64) {
    int i = e >> 5, j = e & 31;
    float s = 0.f;
    for (int k = 0; k < NX; ++k) s += As[i*STRD+k] * Ps[k*STRD+j];
    aps[i*STRD+j] = s;
    apG[e] = s;
  }
  wsync();
  for (int e = t; e < NX*NX; e += 64) {
    int i = e >> 5, j = e & 31;
    float s = 0.f;
    for (int k = 0; k < NX; ++k) s += aps[i*STRD+k] * As[j*STRD+k];
    apatG[e] = s;
  }
}

// ---------------- forward: chunked Riccati scan ----------------
// one wave per chunk. Matmul phases: lane owns (i = half+2m, j = lane), m=0..15.
// LDL/zeta in registers (lane r = t&31 owns row r; readlane broadcasts).
// Global layouts (consumed by bwd):
//   xOut:  column-major per r:  x[r][c*32 + i]        = xi[i][c]   (lane c stores 32 contig)
//   offOut: permuted col-major: off[r][c*32 + PIDX(i)] = off[i][c] (thread stores 16 contig)
// LDS: smx serves S-matrix (S-phase->row-load) then xi (zeta->off-phase) — disjoint lifetimes.
// offP[k*OPSTRD + PIDX(i)] = off[i][k]: read by u-phase (prev step), pred-phase; b128 rows.
template<typename ST>
__global__ __launch_bounds__(64, 2) void fwd_kernel(
    const float* __restrict__ hessAll, const float* __restrict__ gradAll,
    const float* __restrict__ apG, const float* __restrict__ apatG,
    const float* __restrict__ P, const float* __restrict__ initP,
    ST* __restrict__ offOut, ST* __restrict__ xOut, float* __restrict__ uOut)
{
  __shared__ float apP[NX*32], smx[NX*STRD], offP[NX*OPSTRD];
  __shared__ float uv[NX], tv[NX];
  const int t = threadIdx.x;
  const int lane = t & 31, half = t >> 5;
  const int pl = PIDX(lane);
  const int c = blockIdx.x;
  const int r0 = c * CHUNKF, r1 = r0 + CHUNKF;

  float PsR[16], apatR[16], predR[16], hessR[16];
  float gradR;

  const int cl = 16*(lane & 1) + (lane >> 1);   // permuted-column map
  #pragma unroll
  for (int m = 0; m < 16; ++m) {
    int e = t + 64*m;
    apP[(half + 2*m)*32 + cl] = apG[e];
    PsR[m]   = P[e];
    apatR[m] = apatG[e];
  }
  for (int e = t; e < NX*OPSTRD; e += 64) offP[e] = 0.f;
  wsync();

  int rstart = r0 - WARM;
  if (rstart < 0) rstart = 0;
  const bool exact = (rstart == 0);

  #pragma unroll
  for (int m = 0; m < 16; ++m)
    predR[m] = exact ? initP[t + 64*m] : PsR[m];   // any SPD init works (contraction)
  if (t < NX) uv[t] = 0.f;
  wsync();

  // preload first step's hess/grad
  {
    const float* hess = hessAll + (size_t)rstart * (NX*NX);
    #pragma unroll
    for (int m = 0; m < 16; ++m) hessR[m] = hess[t + 64*m];
    gradR = gradAll[(size_t)rstart * NX + lane];
  }

  for (int r = rstart; r < r1; ++r) {
    const bool last = (r == R_TOT-1);
    // ---- S = pred + hess (+ apat) into smx ----
    #pragma unroll
    for (int m = 0; m < 16; ++m) {
      float v = predR[m] + hessR[m];
      if (!last) v += apatR[m];
      smx[(half + 2*m)*STRD + lane] = v;
    }
    wsync();
    // prefetch next step's hess (latency hidden under LDL/zeta)
    if (r + 1 < r1) {
      const float* hn = hessAll + (size_t)(r+1) * (NX*NX);
      #pragma unroll
      for (int m = 0; m < 16; ++m) hessR[m] = hn[t + 64*m];
    }
    // ---- row-load: lane r = t&31 takes row r (upper half mirrors) ----
    float row[NX];
    #pragma unroll
    for (int k = 0; k < NX; ++k) row[k] = smx[lane*STRD + k];
    // ---- LDL^T in registers, right-looking, unscaled columns: row[c] = l~_rc * d_c ----
    #pragma unroll
    for (int j = 0; j < NX-1; ++j) {
      float invd = __builtin_amdgcn_rcpf(rdlane(row[j], j));
      float f = (lane > j) ? row[j] * invd : 0.f;
      #pragma unroll
      for (int cc = j+1; cc < NX; ++cc)
        row[cc] = fmaf(-f, rdlane(row[cc], j), row[cc]);
    }
    // ---- zeta = D^{-1} L~^{-1} (column `lane` per lane); zcs = chol^{-1} column ----
    float zcs[NX];
    {
      float zc[NX];
      #pragma unroll
      for (int i = 0; i < NX; ++i) {
        float d_i = rdlane(row[i], i);
        float di = __builtin_amdgcn_rcpf(d_i);
        float s = 0.f;
        #pragma unroll
        for (int k = 0; k < i; ++k) s = fmaf(rdlane(row[k], i), zc[k], s);
        zc[i] = (i == lane) ? di : -di * s;
        zcs[i] = zc[i] * __builtin_amdgcn_sqrtf(d_i);
      }
    }
    if (t < NX) {
      #pragma unroll
      for (int i = 0; i < NX; ++i) smx[i*STRD + t] = zcs[i];   // xi into LDS (transpose)
      if (r >= r0) {
        ST* xp = xOut + (size_t)r * (NX*NX) + t*NX;
        st16(xp, zcs);
        st16(xp + 16, zcs + 16);
      }
    }
    wsync();
    // ---- u update: tv = grad - u_prev @ off_prev^T ; u_new = tv @ xi^T ----
    if (t < NX) {
      float s = gradR;
      #pragma unroll 4
      for (int m = 0; m < NX; ++m) s -= uv[m] * offP[m*OPSTRD + pl];   // off_prev[t][m]
      tv[t] = s;
    }
    wsync();
    float unew = 0.f;
    if (t < NX) {
      float s = 0.f;
      #pragma unroll 4
      for (int k = 0; k < NX; ++k) s += tv[k] * smx[t*STRD+k];
      unew = s;
    }
    wsync();
    if (t < NX) {
      uv[t] = unew;
      if (r >= r0) uOut[(size_t)r*NX + t] = unew;
    }
    if (r + 1 < r1) gradR = gradAll[(size_t)(r+1) * NX + lane];
    wsync();   // uv visible; offP reads (u phase) drained before overwrite below
    // ---- off[jj][ii] = -sum_k xi[ii][k] ap[k][jj]; ii = lane, jj = half+2m ----
    {
      float negR[16];
      {
        float offR[16];
        #pragma unroll
        for (int m = 0; m < 16; ++m) offR[m] = 0.f;
        #pragma unroll
        for (int k = 0; k < NX; ++k) {
          float xv = smx[lane*STRD + k];           // xi row `lane`, conflict-free
          const float4* apv = reinterpret_cast<const float4*>(&apP[k*32 + 16*half]);
          float4 a0 = apv[0], a1 = apv[1], a2 = apv[2], a3 = apv[3];   // broadcast b128
          offR[0]  += xv * a0.x; offR[1]  += xv * a0.y; offR[2]  += xv * a0.z; offR[3]  += xv * a0.w;
          offR[4]  += xv * a1.x; offR[5]  += xv * a1.y; offR[6]  += xv * a1.z; offR[7]  += xv * a1.w;
          offR[8]  += xv * a2.x; offR[9]  += xv * a2.y; offR[10] += xv * a2.z; offR[11] += xv * a2.w;
          offR[12] += xv * a3.x; offR[13] += xv * a3.y; offR[14] += xv * a3.z; offR[15] += xv * a3.w;
        }
        #pragma unroll
        for (int m = 0; m < 16; ++m) negR[m] = -offR[m];
      }
      // offP[k=lane][16*half + m] = off[half+2m][lane]
      float4* opw = reinterpret_cast<float4*>(&offP[lane*OPSTRD + 16*half]);
      opw[0] = make_float4(negR[0],  negR[1],  negR[2],  negR[3]);
      opw[1] = make_float4(negR[4],  negR[5],  negR[6],  negR[7]);
      opw[2] = make_float4(negR[8],  negR[9],  negR[10], negR[11]);
      opw[3] = make_float4(negR[12], negR[13], negR[14], negR[15]);
      if (r >= r0)
        st16(offOut + (size_t)r * (NX*NX) + lane*NX + 16*half, negR);
    }
    wsync();
    // ---- pred = P - off @ off^T (into registers) ----
    #pragma unroll
    for (int m = 0; m < 16; ++m) predR[m] = PsR[m];
    #pragma unroll
    for (int k = 0; k < NX; ++k) {
      float fj = offP[k*OPSTRD + pl];              // off[lane][k], conflict-free
      const float4* ov = reinterpret_cast<const float4*>(&offP[k*OPSTRD + 16*half]);
      float4 o0 = ov[0], o1 = ov[1], o2 = ov[2], o3 = ov[3];   // broadcast b128
      predR[0]  -= o0.x*fj; predR[1]  -= o0.y*fj; predR[2]  -= o0.z*fj; predR[3]  -= o0.w*fj;
      predR[4]  -= o1.x*fj; predR[5]  -= o1.y*fj; predR[6]  -= o1.z*fj; predR[7]  -= o1.w*fj;
      predR[8]  -= o2.x*fj; predR[9]  -= o2.y*fj; predR[10] -= o2.z*fj; predR[11] -= o2.w*fj;
      predR[12] -= o3.x*fj; predR[13] -= o3.y*fj; predR[14] -= o3.z*fj; predR[15] -= o3.w*fj;
    }
    wsync();
  }
}

// ---------------- backward: chunked reverse linear scan ----------------
// 256 threads/chunk. Thread owns rows i = grp+8m (grp = t>>5), col j = t&31.
// Staging: thread t loads elements 4t..4t+3 of off[r]/xi[r] (fully coalesced,
// read-once) into regs, deposits to LDS (un-permuting off slots). Per-phase
// column hoists fo[]/fx[] have disjoint live ranges -> no spill (round-3 proven).
// vw/bb use stride VSTRD=36 so rows are 16B-aligned -> b128 broadcast reads.
template<typename ST>
__global__ __launch_bounds__(256, 4) void bwd_kernel(
    const ST* __restrict__ offIn, const ST* __restrict__ xIn, const float* __restrict__ uIn,
    const float* __restrict__ epsx, float* __restrict__ outp)
{
  __shared__ float vw[(NM+1)*VSTRD], bb[(NM+1)*VSTRD], off[NX*STRD], xi[NX*STRD];
  const int t = threadIdx.x;
  const int lane = t & 31, grp = t >> 5;
  const int col = t >> 3, sg = t & 7;   // staging column / slot-group
  const int c = blockIdx.x;
  const int r0 = c * CHUNKB, r1 = r0 + CHUNKB;
  int rstart = r1 + WARM; if (rstart > R_TOT) rstart = R_TOT;
  const bool has64 = (grp == 0);

  for (int e = t; e < (NM+1)*VSTRD; e += 256) vw[e] = 0.f;

  float ov[4], xv[4], gR[9];
  {
    int r = rstart - 1;
    size_t sb = (size_t)r * (NX*NX) + col*NX + 4*sg;
    ld4(ov, offIn + sb);
    ld4(xv, xIn + sb);
    const float* eps_r = epsx + (size_t)r * (NM*NX);
    const float* u_r   = uIn + (size_t)r * NX;
    #pragma unroll
    for (int m = 0; m < 8; ++m) {
      int i = grp + 8*m;
      gR[m] = (i == 0) ? u_r[lane] : eps_r[(i-1)*NX + lane];
    }
    gR[8] = has64 ? eps_r[63*NX + lane] : 0.f;
  }
  __syncthreads();

  for (int r = rstart - 1; r >= r0; --r) {
    float acc[9];
    #pragma unroll
    for (int m = 0; m < 9; ++m) acc[m] = gR[m];
    // ---- deposit this step's off/xi (un-permute off: slot s -> row i) ----
    #pragma unroll
    for (int q = 0; q < 4; ++q) {
      int s = 4*sg + q;
      int io = ((s >> 4) & 1) | ((s & 15) << 1);   // PIDX inverse
      off[io*STRD + col] = ov[q];
      xi[s*STRD + col]   = xv[q];
    }
    __syncthreads();
    // ---- prefetch next (lower) step's inputs ----
    if (r > r0) {
      size_t sb = (size_t)(r-1) * (NX*NX) + col*NX + 4*sg;
      ld4(ov, offIn + sb);
      ld4(xv, xIn + sb);
      const float* eps_n = epsx + (size_t)(r-1) * (NM*NX);
      const float* u_n   = uIn + (size_t)(r-1) * NX;
      #pragma unroll
      for (int m = 0; m < 8; ++m) {
        int i = grp + 8*m;
        gR[m] = (i == 0) ? u_n[lane] : eps_n[(i-1)*NX + lane];
      }
      if (has64) gR[8] = eps_n[63*NX + lane];
    }
    // ---- bb = g - vw @ off : hoist off column into regs, b128 the vw rows ----
    {
      float fo[NX];
      #pragma unroll
      for (int k = 0; k < NX; ++k) fo[k] = off[k*STRD + lane];   // 2-way = free
      #pragma unroll
      for (int m = 0; m < 8; ++m) {
        const float4* vr = reinterpret_cast<const float4*>(&vw[(grp + 8*m)*VSTRD]);
        #pragma unroll
        for (int q = 0; q < 8; ++q) {
          float4 v4 = vr[q];                    // broadcast b128
          acc[m] -= v4.x*fo[4*q] + v4.y*fo[4*q+1] + v4.z*fo[4*q+2] + v4.w*fo[4*q+3];
        }
      }
      if (has64) {
        const float4* vr = reinterpret_cast<const float4*>(&vw[64*VSTRD]);
        #pragma unroll
        for (int q = 0; q < 8; ++q) {
          float4 v4 = vr[q];
          acc[8] -= v4.x*fo[4*q] + v4.y*fo[4*q+1] + v4.z*fo[4*q+2] + v4.w*fo[4*q+3];
        }
      }
    }
    #pragma unroll
    for (int m = 0; m < 8; ++m) bb[(grp + 8*m)*VSTRD + lane] = acc[m];
    if (has64) bb[64*VSTRD + lane] = acc[8];
    __syncthreads();
    // ---- vw = bb @ xi : hoist xi column into regs, b128 the bb rows ----
    float vacc[9];
    #pragma unroll
    for (int m = 0; m < 9; ++m) vacc[m] = 0.f;
    {
      float fx[NX];
      #pragma unroll
      for (int k = 0; k < NX; ++k) fx[k] = xi[k*STRD + lane];    // 2-way = free
      #pragma unroll
      for (int m = 0; m < 8; ++m) {
        const float4* br = reinterpret_cast<const float4*>(&bb[(grp + 8*m)*VSTRD]);
        #pragma unroll
        for (int q = 0; q < 8; ++q) {
          float4 b4 = br[q];                    // broadcast b128
          vacc[m] += b4.x*fx[4*q] + b4.y*fx[4*q+1] + b4.z*fx[4*q+2] + b4.w*fx[4*q+3];
        }
      }
      if (has64) {
        const float4* br = reinterpret_cast<const float4*>(&bb[64*VSTRD]);
        #pragma unroll
        for (int q = 0; q < 8; ++q) {
          float4 b4 = br[q];
          vacc[8] += b4.x*fx[4*q] + b4.y*fx[4*q+1] + b4.z*fx[4*q+2] + b4.w*fx[4*q+3];
        }
      }
    }
    #pragma unroll
    for (int m = 0; m < 8; ++m) vw[(grp + 8*m)*VSTRD + lane] = vacc[m];
    if (has64) vw[64*VSTRD + lane] = vacc[8];
    __syncthreads();
    // ---- out_r[i][j] = vw[i+1][j] + vw[0][j], rows i = grp+8m ----
    if (r < r1) {
      float v0 = vw[lane];
      float* out_r = outp + (size_t)r * (NM*NX);
      #pragma unroll
      for (int m = 0; m < 8; ++m)
        out_r[(grp + 8*m)*NX + lane] = vw[(grp + 8*m + 1)*VSTRD + lane] + v0;
    }
    // no trailing barrier: vw reads here are fenced by next iteration's barriers
    // before any vw write; off/xi deposits are fenced by the post-vw barrier above.
  }
}

extern "C" void kernel_launch(void* const* d_in, const int* in_sizes, int n_in,
                              void* d_out, int out_size, void* d_ws, size_t ws_size,
                              hipStream_t stream) {
  const float* hess  = (const float*)d_in[0];
  const float* grads = (const float*)d_in[1];
  const float* A     = (const float*)d_in[2];
  const float* P     = (const float*)d_in[3];
  const float* initP = (const float*)d_in[4];
  const float* epsx  = (const float*)d_in[5];
  float* outp = (float*)d_out;

  const size_t mats = (size_t)R_TOT * NX * NX;
  const size_t uN   = (size_t)R_TOT * NX;
  const size_t needF32 = 2ull * mats * sizeof(float) + uN * sizeof(float) + 2048 * sizeof(float);

  if (ws_size >= needF32) {
    float* offS  = (float*)d_ws;
    float* xS    = offS + mats;
    float* uS    = xS + mats;
    float* apG   = uS + uN;
    float* apatG = apG + 1024;
    precomp_kernel<<<dim3(1), dim3(64), 0, stream>>>(A, P, apG, apatG);
    fwd_kernel<float><<<dim3(R_TOT/CHUNKF), dim3(64), 0, stream>>>(
        hess, grads, apG, apatG, P, initP, offS, xS, uS);
    bwd_kernel<float><<<dim3(R_TOT/CHUNKB), dim3(256), 0, stream>>>(
        offS, xS, uS, epsx, outp);
  } else {
    __hip_bfloat16* offS = (__hip_bfloat16*)d_ws;
    __hip_bfloat16* xS   = offS + mats;
    float* uS            = (float*)(xS + mats);
    float* apG           = uS + uN;
    float* apatG         = apG + 1024;
    precomp_kernel<<<dim3(1), dim3(64), 0, stream>>>(A, P, apG, apatG);
    fwd_kernel<__hip_bfloat16><<<dim3(R_TOT/CHUNKF), dim3(64), 0, stream>>>(
        hess, grads, apG, apatG, P, initP, offS, xS, uS);
    bwd_kernel<__hip_bfloat16><<<dim3(R_TOT/CHUNKB), dim3(256), 0, stream>>>(
        offS, xS, uS, epsx, outp);
  }
}

// Round 7
// 470.637 us; speedup vs baseline: 4.6009x; 1.1970x over previous
//
#include <hip/hip_runtime.h>
#include <hip/hip_bf16.h>

#define R_TOT 8192
#define NX 32
#define NM 64
#define STRD 33
#define VSTRD 36
#define OPSTRD 36
#define WARMF 8
#define WARMB 8
#define CHUNKF 4
#define CHUNKB 16

// permuted row index within a stored column: slot of row r is PIDX(r)
#define PIDX(k) ((((k) & 1) << 4) | ((k) >> 1))

// single-wave "barrier": lockstep wave64 + drain LDS ops. Valid only for 64-thread blocks.
__device__ inline void wsync() { asm volatile("s_waitcnt lgkmcnt(0)" ::: "memory"); }

// wave-uniform broadcast of lane l's value (l compile-time)
__device__ inline float rdlane(float v, int l) {
  return __uint_as_float(__builtin_amdgcn_readlane(__float_as_uint(v), l));
}

// ---- bf16 bit helpers (RNE) ----
__device__ inline unsigned f2bf(float x) {
  unsigned u = __float_as_uint(x);
  return (u + 0x7fffu + ((u >> 16) & 1u)) >> 16;
}

// ---- 16-element vector store (float or bf16 storage) ----
__device__ inline void st16(float* g, const float* v) {
  float4* p = reinterpret_cast<float4*>(g);
  p[0] = make_float4(v[0], v[1], v[2], v[3]);
  p[1] = make_float4(v[4], v[5], v[6], v[7]);
  p[2] = make_float4(v[8], v[9], v[10], v[11]);
  p[3] = make_float4(v[12], v[13], v[14], v[15]);
}
__device__ inline void st16(__hip_bfloat16* g, const float* v) {
  unsigned w[8];
  #pragma unroll
  for (int q = 0; q < 8; ++q)
    w[q] = (f2bf(v[2*q+1]) << 16) | f2bf(v[2*q]);
  uint4* p = reinterpret_cast<uint4*>(g);
  p[0] = make_uint4(w[0], w[1], w[2], w[3]);
  p[1] = make_uint4(w[4], w[5], w[6], w[7]);
}

// ---- 4-element vector load (float or bf16 storage) ----
__device__ inline void ld4(float* v, const float* g) {
  float4 a = *reinterpret_cast<const float4*>(g);
  v[0] = a.x; v[1] = a.y; v[2] = a.z; v[3] = a.w;
}
__device__ inline void ld4(float* v, const __hip_bfloat16* g) {
  uint2 a = *reinterpret_cast<const uint2*>(g);
  v[0] = __uint_as_float(a.x << 16);
  v[1] = __uint_as_float(a.x & 0xffff0000u);
  v[2] = __uint_as_float(a.y << 16);
  v[3] = __uint_as_float(a.y & 0xffff0000u);
}

// ---------------- precompute ap = A@P, apat = ap@A^T (shared by all chunks) --------------
__global__ __launch_bounds__(64) void precomp_kernel(
    const float* __restrict__ A, const float* __restrict__ P,
    float* __restrict__ apG, float* __restrict__ apatG)
{
  __shared__ float As[NX*STRD], Ps[NX*STRD], aps[NX*STRD];
  const int t = threadIdx.x;
  for (int e = t; e < NX*NX; e += 64) {
    int i = e >> 5, j = e & 31;
    As[i*STRD+j] = A[e];
    Ps[i*STRD+j] = P[e];
  }
  wsync();
  for (int e = t; e < NX*NX; e += 64) {
    int i = e >> 5, j = e & 31;
    float s = 0.f;
    for (int k = 0; k < NX; ++k) s += As[i*STRD+k] * Ps[k*STRD+j];
    aps[i*STRD+j] = s;
    apG[e] = s;
  }
  wsync();
  for (int e = t; e < NX*NX; e += 64) {
    int i = e >> 5, j = e & 31;
    float s = 0.f;
    for (int k = 0; k < NX; ++k) s += aps[i*STRD+k] * As[j*STRD+k];
    apatG[e] = s;
  }
}

// ---------------- forward: chunked Riccati scan ----------------
// one wave per chunk. Matmul phases: lane owns (i = half+2m, j = lane), m=0..15.
// LDL/zeta in registers (lane r = t&31 owns row r; readlane broadcasts).
// Global layouts (consumed by bwd):
//   xOut:  column-major per r:  x[r][c*32 + i]        = xi[i][c]   (lane c stores 32 contig)
//   offOut: permuted col-major: off[r][c*32 + PIDX(i)] = off[i][c] (thread stores 16 contig)
// LDS: smx serves S-matrix (S-phase->row-load) then xi (zeta->off-phase) — disjoint lifetimes.
// offP[k*OPSTRD + PIDX(i)] = off[i][k]: read by u-phase (prev step), pred-phase; b128 rows.
template<typename ST>
__global__ __launch_bounds__(64, 2) void fwd_kernel(
    const float* __restrict__ hessAll, const float* __restrict__ gradAll,
    const float* __restrict__ apG, const float* __restrict__ apatG,
    const float* __restrict__ P, const float* __restrict__ initP,
    ST* __restrict__ offOut, ST* __restrict__ xOut, float* __restrict__ uOut)
{
  __shared__ float apP[NX*32], smx[NX*STRD], offP[NX*OPSTRD];
  __shared__ float uv[NX], tv[NX];
  const int t = threadIdx.x;
  const int lane = t & 31, half = t >> 5;
  const int pl = PIDX(lane);
  const int c = blockIdx.x;
  const int r0 = c * CHUNKF, r1 = r0 + CHUNKF;

  float PsR[16], apatR[16], predR[16], hessR[16];
  float gradR;

  const int cl = 16*(lane & 1) + (lane >> 1);   // permuted-column map
  #pragma unroll
  for (int m = 0; m < 16; ++m) {
    int e = t + 64*m;
    apP[(half + 2*m)*32 + cl] = apG[e];
    PsR[m]   = P[e];
    apatR[m] = apatG[e];
  }
  for (int e = t; e < NX*OPSTRD; e += 64) offP[e] = 0.f;
  wsync();

  int rstart = r0 - WARMF;
  if (rstart < 0) rstart = 0;
  const bool exact = (rstart == 0);

  #pragma unroll
  for (int m = 0; m < 16; ++m)
    predR[m] = exact ? initP[t + 64*m] : PsR[m];   // any SPD init works (contraction)
  if (t < NX) uv[t] = 0.f;
  wsync();

  // preload first step's hess/grad
  {
    const float* hess = hessAll + (size_t)rstart * (NX*NX);
    #pragma unroll
    for (int m = 0; m < 16; ++m) hessR[m] = hess[t + 64*m];
    gradR = gradAll[(size_t)rstart * NX + lane];
  }

  for (int r = rstart; r < r1; ++r) {
    const bool last = (r == R_TOT-1);
    // ---- S = pred + hess (+ apat) into smx ----
    #pragma unroll
    for (int m = 0; m < 16; ++m) {
      float v = predR[m] + hessR[m];
      if (!last) v += apatR[m];
      smx[(half + 2*m)*STRD + lane] = v;
    }
    wsync();
    // prefetch next step's hess (latency hidden under LDL/zeta)
    if (r + 1 < r1) {
      const float* hn = hessAll + (size_t)(r+1) * (NX*NX);
      #pragma unroll
      for (int m = 0; m < 16; ++m) hessR[m] = hn[t + 64*m];
    }
    // ---- row-load: lane r = t&31 takes row r (upper half mirrors) ----
    float row[NX];
    #pragma unroll
    for (int k = 0; k < NX; ++k) row[k] = smx[lane*STRD + k];
    // ---- LDL^T in registers, right-looking, unscaled columns: row[c] = l~_rc * d_c ----
    #pragma unroll
    for (int j = 0; j < NX-1; ++j) {
      float invd = __builtin_amdgcn_rcpf(rdlane(row[j], j));
      float f = (lane > j) ? row[j] * invd : 0.f;
      #pragma unroll
      for (int cc = j+1; cc < NX; ++cc)
        row[cc] = fmaf(-f, rdlane(row[cc], j), row[cc]);
    }
    // ---- zeta = D^{-1} L~^{-1} (column `lane` per lane) ----
    float zc[NX];
    #pragma unroll
    for (int i = 0; i < NX; ++i) {
      float d_i = rdlane(row[i], i);
      float di = __builtin_amdgcn_rcpf(d_i);
      float s = 0.f;
      #pragma unroll
      for (int k = 0; k < i; ++k) s = fmaf(rdlane(row[k], i), zc[k], s);
      zc[i] = (i == lane) ? di : -di * s;
    }
    // rescale in place to chol^{-1} rows (kills the second 32-reg array; row dies here)
    #pragma unroll
    for (int i = 0; i < NX; ++i)
      zc[i] *= __builtin_amdgcn_sqrtf(rdlane(row[i], i));
    if (t < NX) {
      #pragma unroll
      for (int i = 0; i < NX; ++i) smx[i*STRD + t] = zc[i];   // xi into LDS (transpose)
      if (r >= r0) {
        ST* xp = xOut + (size_t)r * (NX*NX) + t*NX;
        st16(xp, zc);
        st16(xp + 16, zc + 16);
      }
    }
    wsync();
    // ---- u update: tv = grad - u_prev @ off_prev^T ; u_new = tv @ xi^T ----
    if (t < NX) {
      float s = gradR;
      #pragma unroll 4
      for (int m = 0; m < NX; ++m) s -= uv[m] * offP[m*OPSTRD + pl];   // off_prev[t][m]
      tv[t] = s;
    }
    wsync();
    float unew = 0.f;
    if (t < NX) {
      float s = 0.f;
      #pragma unroll 4
      for (int k = 0; k < NX; ++k) s += tv[k] * smx[t*STRD+k];
      unew = s;
    }
    wsync();
    if (t < NX) {
      uv[t] = unew;
      if (r >= r0) uOut[(size_t)r*NX + t] = unew;
    }
    if (r + 1 < r1) gradR = gradAll[(size_t)(r+1) * NX + lane];
    wsync();   // uv visible; offP reads (u phase) drained before overwrite below
    // ---- off[jj][ii] = -sum_k xi[ii][k] ap[k][jj]; ii = lane, jj = half+2m ----
    // negation folded into the FMA accumulation (neg modifier is free)
    {
      float offR[16];
      #pragma unroll
      for (int m = 0; m < 16; ++m) offR[m] = 0.f;
      #pragma unroll
      for (int k = 0; k < NX; ++k) {
        float xv = smx[lane*STRD + k];           // xi row `lane`, conflict-free
        const float4* apv = reinterpret_cast<const float4*>(&apP[k*32 + 16*half]);
        float4 a0 = apv[0], a1 = apv[1], a2 = apv[2], a3 = apv[3];   // broadcast b128
        offR[0]  = fmaf(-xv, a0.x, offR[0]);  offR[1]  = fmaf(-xv, a0.y, offR[1]);
        offR[2]  = fmaf(-xv, a0.z, offR[2]);  offR[3]  = fmaf(-xv, a0.w, offR[3]);
        offR[4]  = fmaf(-xv, a1.x, offR[4]);  offR[5]  = fmaf(-xv, a1.y, offR[5]);
        offR[6]  = fmaf(-xv, a1.z, offR[6]);  offR[7]  = fmaf(-xv, a1.w, offR[7]);
        offR[8]  = fmaf(-xv, a2.x, offR[8]);  offR[9]  = fmaf(-xv, a2.y, offR[9]);
        offR[10] = fmaf(-xv, a2.z, offR[10]); offR[11] = fmaf(-xv, a2.w, offR[11]);
        offR[12] = fmaf(-xv, a3.x, offR[12]); offR[13] = fmaf(-xv, a3.y, offR[13]);
        offR[14] = fmaf(-xv, a3.z, offR[14]); offR[15] = fmaf(-xv, a3.w, offR[15]);
      }
      // offP[k=lane][16*half + m] = off[half+2m][lane]
      float4* opw = reinterpret_cast<float4*>(&offP[lane*OPSTRD + 16*half]);
      opw[0] = make_float4(offR[0],  offR[1],  offR[2],  offR[3]);
      opw[1] = make_float4(offR[4],  offR[5],  offR[6],  offR[7]);
      opw[2] = make_float4(offR[8],  offR[9],  offR[10], offR[11]);
      opw[3] = make_float4(offR[12], offR[13], offR[14], offR[15]);
      if (r >= r0)
        st16(offOut + (size_t)r * (NX*NX) + lane*NX + 16*half, offR);
    }
    wsync();
    // ---- pred = P - off @ off^T (into registers) ----
    #pragma unroll
    for (int m = 0; m < 16; ++m) predR[m] = PsR[m];
    #pragma unroll
    for (int k = 0; k < NX; ++k) {
      float fj = offP[k*OPSTRD + pl];              // off[lane][k], conflict-free
      const float4* ov = reinterpret_cast<const float4*>(&offP[k*OPSTRD + 16*half]);
      float4 o0 = ov[0], o1 = ov[1], o2 = ov[2], o3 = ov[3];   // broadcast b128
      predR[0]  -= o0.x*fj; predR[1]  -= o0.y*fj; predR[2]  -= o0.z*fj; predR[3]  -= o0.w*fj;
      predR[4]  -= o1.x*fj; predR[5]  -= o1.y*fj; predR[6]  -= o1.z*fj; predR[7]  -= o1.w*fj;
      predR[8]  -= o2.x*fj; predR[9]  -= o2.y*fj; predR[10] -= o2.z*fj; predR[11] -= o2.w*fj;
      predR[12] -= o3.x*fj; predR[13] -= o3.y*fj; predR[14] -= o3.z*fj; predR[15] -= o3.w*fj;
    }
    wsync();
  }
}

// ---------------- backward: chunked reverse linear scan ----------------
// 256 threads/chunk. Thread owns rows i = grp+8m (grp = t>>5), col j = t&31.
// Staging: thread t loads elements 4t..4t+3 of off[r]/xi[r] (fully coalesced,
// read-once) into regs, deposits to LDS (un-permuting off slots). Per-phase
// column hoists fo[]/fx[] have disjoint live ranges -> no spill (round-3 proven).
// vw/bb use stride VSTRD=36 so rows are 16B-aligned -> b128 broadcast reads.
template<typename ST>
__global__ __launch_bounds__(256, 4) void bwd_kernel(
    const ST* __restrict__ offIn, const ST* __restrict__ xIn, const float* __restrict__ uIn,
    const float* __restrict__ epsx, float* __restrict__ outp)
{
  __shared__ float vw[(NM+1)*VSTRD], bb[(NM+1)*VSTRD], off[NX*STRD], xi[NX*STRD];
  const int t = threadIdx.x;
  const int lane = t & 31, grp = t >> 5;
  const int col = t >> 3, sg = t & 7;   // staging column / slot-group
  const int c = blockIdx.x;
  const int r0 = c * CHUNKB, r1 = r0 + CHUNKB;
  int rstart = r1 + WARMB; if (rstart > R_TOT) rstart = R_TOT;
  const bool has64 = (grp == 0);

  for (int e = t; e < (NM+1)*VSTRD; e += 256) vw[e] = 0.f;

  float ov[4], xv[4], gR[9];
  {
    int r = rstart - 1;
    size_t sb = (size_t)r * (NX*NX) + col*NX + 4*sg;
    ld4(ov, offIn + sb);
    ld4(xv, xIn + sb);
    const float* eps_r = epsx + (size_t)r * (NM*NX);
    const float* u_r   = uIn + (size_t)r * NX;
    #pragma unroll
    for (int m = 0; m < 8; ++m) {
      int i = grp + 8*m;
      gR[m] = (i == 0) ? u_r[lane] : eps_r[(i-1)*NX + lane];
    }
    gR[8] = has64 ? eps_r[63*NX + lane] : 0.f;
  }
  __syncthreads();

  for (int r = rstart - 1; r >= r0; --r) {
    float acc[9];
    #pragma unroll
    for (int m = 0; m < 9; ++m) acc[m] = gR[m];
    // ---- deposit this step's off/xi (un-permute off: slot s -> row i) ----
    #pragma unroll
    for (int q = 0; q < 4; ++q) {
      int s = 4*sg + q;
      int io = ((s >> 4) & 1) | ((s & 15) << 1);   // PIDX inverse
      off[io*STRD + col] = ov[q];
      xi[s*STRD + col]   = xv[q];
    }
    __syncthreads();
    // ---- prefetch next (lower) step's inputs ----
    if (r > r0) {
      size_t sb = (size_t)(r-1) * (NX*NX) + col*NX + 4*sg;
      ld4(ov, offIn + sb);
      ld4(xv, xIn + sb);
      const float* eps_n = epsx + (size_t)(r-1) * (NM*NX);
      const float* u_n   = uIn + (size_t)(r-1) * NX;
      #pragma unroll
      for (int m = 0; m < 8; ++m) {
        int i = grp + 8*m;
        gR[m] = (i == 0) ? u_n[lane] : eps_n[(i-1)*NX + lane];
      }
      if (has64) gR[8] = eps_n[63*NX + lane];
    }
    // ---- bb = g - vw @ off : hoist off column into regs, b128 the vw rows ----
    {
      float fo[NX];
      #pragma unroll
      for (int k = 0; k < NX; ++k) fo[k] = off[k*STRD + lane];   // 2-way = free
      #pragma unroll
      for (int m = 0; m < 8; ++m) {
        const float4* vr = reinterpret_cast<const float4*>(&vw[(grp + 8*m)*VSTRD]);
        #pragma unroll
        for (int q = 0; q < 8; ++q) {
          float4 v4 = vr[q];                    // broadcast b128
          acc[m] -= v4.x*fo[4*q] + v4.y*fo[4*q+1] + v4.z*fo[4*q+2] + v4.w*fo[4*q+3];
        }
      }
      if (has64) {
        const float4* vr = reinterpret_cast<const float4*>(&vw[64*VSTRD]);
        #pragma unroll
        for (int q = 0; q < 8; ++q) {
          float4 v4 = vr[q];
          acc[8] -= v4.x*fo[4*q] + v4.y*fo[4*q+1] + v4.z*fo[4*q+2] + v4.w*fo[4*q+3];
        }
      }
    }
    #pragma unroll
    for (int m = 0; m < 8; ++m) bb[(grp + 8*m)*VSTRD + lane] = acc[m];
    if (has64) bb[64*VSTRD + lane] = acc[8];
    __syncthreads();
    // ---- vw = bb @ xi : hoist xi column into regs, b128 the bb rows ----
    float vacc[9];
    #pragma unroll
    for (int m = 0; m < 9; ++m) vacc[m] = 0.f;
    {
      float fx[NX];
      #pragma unroll
      for (int k = 0; k < NX; ++k) fx[k] = xi[k*STRD + lane];    // 2-way = free
      #pragma unroll
      for (int m = 0; m < 8; ++m) {
        const float4* br = reinterpret_cast<const float4*>(&bb[(grp + 8*m)*VSTRD]);
        #pragma unroll
        for (int q = 0; q < 8; ++q) {
          float4 b4 = br[q];                    // broadcast b128
          vacc[m] += b4.x*fx[4*q] + b4.y*fx[4*q+1] + b4.z*fx[4*q+2] + b4.w*fx[4*q+3];
        }
      }
      if (has64) {
        const float4* br = reinterpret_cast<const float4*>(&bb[64*VSTRD]);
        #pragma unroll
        for (int q = 0; q < 8; ++q) {
          float4 b4 = br[q];
          vacc[8] += b4.x*fx[4*q] + b4.y*fx[4*q+1] + b4.z*fx[4*q+2] + b4.w*fx[4*q+3];
        }
      }
    }
    #pragma unroll
    for (int m = 0; m < 8; ++m) vw[(grp + 8*m)*VSTRD + lane] = vacc[m];
    if (has64) vw[64*VSTRD + lane] = vacc[8];
    __syncthreads();
    // ---- out_r[i][j] = vw[i+1][j] + vw[0][j], rows i = grp+8m ----
    if (r < r1) {
      float v0 = vw[lane];
      float* out_r = outp + (size_t)r * (NM*NX);
      #pragma unroll
      for (int m = 0; m < 8; ++m)
        out_r[(grp + 8*m)*NX + lane] = vw[(grp + 8*m + 1)*VSTRD + lane] + v0;
    }
    // no trailing barrier: vw reads here are fenced by next iteration's barriers
    // before any vw write; off/xi deposits are fenced by the post-vw barrier above.
  }
}

extern "C" void kernel_launch(void* const* d_in, const int* in_sizes, int n_in,
                              void* d_out, int out_size, void* d_ws, size_t ws_size,
                              hipStream_t stream) {
  const float* hess  = (const float*)d_in[0];
  const float* grads = (const float*)d_in[1];
  const float* A     = (const float*)d_in[2];
  const float* P     = (const float*)d_in[3];
  const float* initP = (const float*)d_in[4];
  const float* epsx  = (const float*)d_in[5];
  float* outp = (float*)d_out;

  const size_t mats = (size_t)R_TOT * NX * NX;
  const size_t uN   = (size_t)R_TOT * NX;
  const size_t needF32 = 2ull * mats * sizeof(float) + uN * sizeof(float) + 2048 * sizeof(float);

  if (ws_size >= needF32) {
    float* offS  = (float*)d_ws;
    float* xS    = offS + mats;
    float* uS    = xS + mats;
    float* apG   = uS + uN;
    float* apatG = apG + 1024;
    precomp_kernel<<<dim3(1), dim3(64), 0, stream>>>(A, P, apG, apatG);
    fwd_kernel<float><<<dim3(R_TOT/CHUNKF), dim3(64), 0, stream>>>(
        hess, grads, apG, apatG, P, initP, offS, xS, uS);
    bwd_kernel<float><<<dim3(R_TOT/CHUNKB), dim3(256), 0, stream>>>(
        offS, xS, uS, epsx, outp);
  } else {
    __hip_bfloat16* offS = (__hip_bfloat16*)d_ws;
    __hip_bfloat16* xS   = offS + mats;
    float* uS            = (float*)(xS + mats);
    float* apG           = uS + uN;
    float* apatG         = apG + 1024;
    precomp_kernel<<<dim3(1), dim3(64), 0, stream>>>(A, P, apG, apatG);
    fwd_kernel<__hip_bfloat16><<<dim3(R_TOT/CHUNKF), dim3(64), 0, stream>>>(
        hess, grads, apG, apatG, P, initP, offS, xS, uS);
    bwd_kernel<__hip_bfloat16><<<dim3(R_TOT/CHUNKB), dim3(256), 0, stream>>>(
        offS, xS, uS, epsx, outp);
  }
}

// Round 10
// 463.268 us; speedup vs baseline: 4.6740x; 1.0159x over previous
//
#include <hip/hip_runtime.h>
#include <hip/hip_bf16.h>

#define R_TOT 8192
#define NX 32
#define NM 64
#define STRD 33
#define VSTRD 36
#define OPSTRD 36
#define WARMF 8
#define WARMB 8
#define CHUNKF 4
#define CHUNKB 8

// permuted row index within a stored column: slot of row r is PIDX(r)
#define PIDX(k) ((((k) & 1) << 4) | ((k) >> 1))

// single-wave "barrier": lockstep wave64 + drain LDS ops. Valid only for 64-thread blocks.
__device__ inline void wsync() { asm volatile("s_waitcnt lgkmcnt(0)" ::: "memory"); }

// wave-uniform broadcast of lane l's value (l compile-time)
__device__ inline float rdlane(float v, int l) {
  return __uint_as_float(__builtin_amdgcn_readlane(__float_as_uint(v), l));
}

// ---- bf16 bit helpers (RNE) ----
__device__ inline unsigned f2bf(float x) {
  unsigned u = __float_as_uint(x);
  return (u + 0x7fffu + ((u >> 16) & 1u)) >> 16;
}

// ---- 16-element vector store (float or bf16 storage) ----
__device__ inline void st16(float* g, const float* v) {
  float4* p = reinterpret_cast<float4*>(g);
  p[0] = make_float4(v[0], v[1], v[2], v[3]);
  p[1] = make_float4(v[4], v[5], v[6], v[7]);
  p[2] = make_float4(v[8], v[9], v[10], v[11]);
  p[3] = make_float4(v[12], v[13], v[14], v[15]);
}
__device__ inline void st16(__hip_bfloat16* g, const float* v) {
  unsigned w[8];
  #pragma unroll
  for (int q = 0; q < 8; ++q)
    w[q] = (f2bf(v[2*q+1]) << 16) | f2bf(v[2*q]);
  uint4* p = reinterpret_cast<uint4*>(g);
  p[0] = make_uint4(w[0], w[1], w[2], w[3]);
  p[1] = make_uint4(w[4], w[5], w[6], w[7]);
}

// ---- 4-element vector load (float or bf16 storage) ----
__device__ inline void ld4(float* v, const float* g) {
  float4 a = *reinterpret_cast<const float4*>(g);
  v[0] = a.x; v[1] = a.y; v[2] = a.z; v[3] = a.w;
}
__device__ inline void ld4(float* v, const __hip_bfloat16* g) {
  uint2 a = *reinterpret_cast<const uint2*>(g);
  v[0] = __uint_as_float(a.x << 16);
  v[1] = __uint_as_float(a.x & 0xffff0000u);
  v[2] = __uint_as_float(a.y << 16);
  v[3] = __uint_as_float(a.y & 0xffff0000u);
}

// ---------------- precompute ap = A@P, apat = ap@A^T (shared by all chunks) --------------
__global__ __launch_bounds__(64) void precomp_kernel(
    const float* __restrict__ A, const float* __restrict__ P,
    float* __restrict__ apG, float* __restrict__ apatG)
{
  __shared__ float As[NX*STRD], Ps[NX*STRD], aps[NX*STRD];
  const int t = threadIdx.x;
  for (int e = t; e < NX*NX; e += 64) {
    int i = e >> 5, j = e & 31;
    As[i*STRD+j] = A[e];
    Ps[i*STRD+j] = P[e];
  }
  wsync();
  for (int e = t; e < NX*NX; e += 64) {
    int i = e >> 5, j = e & 31;
    float s = 0.f;
    for (int k = 0; k < NX; ++k) s += As[i*STRD+k] * Ps[k*STRD+j];
    aps[i*STRD+j] = s;
    apG[e] = s;
  }
  wsync();
  for (int e = t; e < NX*NX; e += 64) {
    int i = e >> 5, j = e & 31;
    float s = 0.f;
    for (int k = 0; k < NX; ++k) s += aps[i*STRD+k] * As[j*STRD+k];
    apatG[e] = s;
  }
}

// ---------------- forward: chunked Riccati scan ----------------
// one wave per chunk. Matmul phases: lane owns (i = half+2m, j = lane), m=0..15.
// LDL/zeta in registers (lane r = t&31 owns row r; readlane broadcasts).
// Global layouts (consumed by bwd):
//   xOut:  column-major per r:  x[r][c*32 + i]        = xi[i][c]   (lane c stores 32 contig)
//   offOut: permuted col-major: off[r][c*32 + PIDX(i)] = off[i][c] (thread stores 16 contig)
// LDS: smx serves S-matrix (S-phase->row-load) then xi (zeta->off-phase) — disjoint lifetimes.
// offP[k*OPSTRD + PIDX(i)] = off[i][k]: read by u-phase (prev step), pred-phase; b128 rows.
template<typename ST>
__global__ __launch_bounds__(64, 2) void fwd_kernel(
    const float* __restrict__ hessAll, const float* __restrict__ gradAll,
    const float* __restrict__ apG, const float* __restrict__ apatG,
    const float* __restrict__ P, const float* __restrict__ initP,
    ST* __restrict__ offOut, ST* __restrict__ xOut, float* __restrict__ uOut)
{
  __shared__ float apP[NX*32], smx[NX*STRD], offP[NX*OPSTRD];
  __shared__ float uv[NX], tv[NX];
  const int t = threadIdx.x;
  const int lane = t & 31, half = t >> 5;
  const int pl = PIDX(lane);
  const int c = blockIdx.x;
  const int r0 = c * CHUNKF, r1 = r0 + CHUNKF;

  float PsR[16], apatR[16], predR[16], hessR[16];
  float gradR;

  const int cl = 16*(lane & 1) + (lane >> 1);   // permuted-column map
  #pragma unroll
  for (int m = 0; m < 16; ++m) {
    int e = t + 64*m;
    apP[(half + 2*m)*32 + cl] = apG[e];
    PsR[m]   = P[e];
    apatR[m] = apatG[e];
  }
  for (int e = t; e < NX*OPSTRD; e += 64) offP[e] = 0.f;
  wsync();

  int rstart = r0 - WARMF;
  if (rstart < 0) rstart = 0;
  const bool exact = (rstart == 0);

  #pragma unroll
  for (int m = 0; m < 16; ++m)
    predR[m] = exact ? initP[t + 64*m] : PsR[m];   // any SPD init works (contraction)
  if (t < NX) uv[t] = 0.f;
  wsync();

  // preload first step's hess/grad
  {
    const float* hess = hessAll + (size_t)rstart * (NX*NX);
    #pragma unroll
    for (int m = 0; m < 16; ++m) hessR[m] = hess[t + 64*m];
    gradR = gradAll[(size_t)rstart * NX + lane];
  }

  for (int r = rstart; r < r1; ++r) {
    const bool last = (r == R_TOT-1);
    // ---- S = pred + hess (+ apat) into smx ----
    #pragma unroll
    for (int m = 0; m < 16; ++m) {
      float v = predR[m] + hessR[m];
      if (!last) v += apatR[m];
      smx[(half + 2*m)*STRD + lane] = v;
    }
    wsync();
    // prefetch next step's hess (latency hidden under LDL/zeta)
    if (r + 1 < r1) {
      const float* hn = hessAll + (size_t)(r+1) * (NX*NX);
      #pragma unroll
      for (int m = 0; m < 16; ++m) hessR[m] = hn[t + 64*m];
    }
    // ---- row-load: lane r = t&31 takes row r (upper half mirrors) ----
    float row[NX];
    #pragma unroll
    for (int k = 0; k < NX; ++k) row[k] = smx[lane*STRD + k];
    // ---- LDL^T in registers, right-looking, unscaled columns: row[c] = l~_rc * d_c ----
    #pragma unroll
    for (int j = 0; j < NX-1; ++j) {
      float invd = __builtin_amdgcn_rcpf(rdlane(row[j], j));
      float f = (lane > j) ? row[j] * invd : 0.f;
      #pragma unroll
      for (int cc = j+1; cc < NX; ++cc)
        row[cc] = fmaf(-f, rdlane(row[cc], j), row[cc]);
    }
    // ---- zeta = D^{-1} L~^{-1} (column `lane` per lane) ----
    float zc[NX];
    #pragma unroll
    for (int i = 0; i < NX; ++i) {
      float d_i = rdlane(row[i], i);
      float di = __builtin_amdgcn_rcpf(d_i);
      float s = 0.f;
      #pragma unroll
      for (int k = 0; k < i; ++k) s = fmaf(rdlane(row[k], i), zc[k], s);
      zc[i] = (i == lane) ? di : -di * s;
    }
    // rescale in place to chol^{-1} rows (kills the second 32-reg array; row dies here)
    #pragma unroll
    for (int i = 0; i < NX; ++i)
      zc[i] *= __builtin_amdgcn_sqrtf(rdlane(row[i], i));
    if (t < NX) {
      #pragma unroll
      for (int i = 0; i < NX; ++i) smx[i*STRD + t] = zc[i];   // xi into LDS (transpose)
      if (r >= r0) {
        ST* xp = xOut + (size_t)r * (NX*NX) + t*NX;
        st16(xp, zc);
        st16(xp + 16, zc + 16);
      }
    }
    wsync();
    // ---- u update: tv = grad - u_prev @ off_prev^T ; u_new = tv @ xi^T ----
    if (t < NX) {
      float s = gradR;
      #pragma unroll 4
      for (int m = 0; m < NX; ++m) s -= uv[m] * offP[m*OPSTRD + pl];   // off_prev[t][m]
      tv[t] = s;
    }
    wsync();
    float unew = 0.f;
    if (t < NX) {
      float s = 0.f;
      #pragma unroll 4
      for (int k = 0; k < NX; ++k) s += tv[k] * smx[t*STRD+k];
      unew = s;
    }
    wsync();
    if (t < NX) {
      uv[t] = unew;
      if (r >= r0) uOut[(size_t)r*NX + t] = unew;
    }
    if (r + 1 < r1) gradR = gradAll[(size_t)(r+1) * NX + lane];
    wsync();   // uv visible; offP reads (u phase) drained before overwrite below
    // ---- off[jj][ii] = -sum_k xi[ii][k] ap[k][jj]; ii = lane, jj = half+2m ----
    // negation folded into the FMA accumulation (neg modifier is free)
    {
      float offR[16];
      #pragma unroll
      for (int m = 0; m < 16; ++m) offR[m] = 0.f;
      #pragma unroll
      for (int k = 0; k < NX; ++k) {
        float xv = smx[lane*STRD + k];           // xi row `lane`, conflict-free
        const float4* apv = reinterpret_cast<const float4*>(&apP[k*32 + 16*half]);
        float4 a0 = apv[0], a1 = apv[1], a2 = apv[2], a3 = apv[3];   // broadcast b128
        offR[0]  = fmaf(-xv, a0.x, offR[0]);  offR[1]  = fmaf(-xv, a0.y, offR[1]);
        offR[2]  = fmaf(-xv, a0.z, offR[2]);  offR[3]  = fmaf(-xv, a0.w, offR[3]);
        offR[4]  = fmaf(-xv, a1.x, offR[4]);  offR[5]  = fmaf(-xv, a1.y, offR[5]);
        offR[6]  = fmaf(-xv, a1.z, offR[6]);  offR[7]  = fmaf(-xv, a1.w, offR[7]);
        offR[8]  = fmaf(-xv, a2.x, offR[8]);  offR[9]  = fmaf(-xv, a2.y, offR[9]);
        offR[10] = fmaf(-xv, a2.z, offR[10]); offR[11] = fmaf(-xv, a2.w, offR[11]);
        offR[12] = fmaf(-xv, a3.x, offR[12]); offR[13] = fmaf(-xv, a3.y, offR[13]);
        offR[14] = fmaf(-xv, a3.z, offR[14]); offR[15] = fmaf(-xv, a3.w, offR[15]);
      }
      // offP[k=lane][16*half + m] = off[half+2m][lane]
      float4* opw = reinterpret_cast<float4*>(&offP[lane*OPSTRD + 16*half]);
      opw[0] = make_float4(offR[0],  offR[1],  offR[2],  offR[3]);
      opw[1] = make_float4(offR[4],  offR[5],  offR[6],  offR[7]);
      opw[2] = make_float4(offR[8],  offR[9],  offR[10], offR[11]);
      opw[3] = make_float4(offR[12], offR[13], offR[14], offR[15]);
      if (r >= r0)
        st16(offOut + (size_t)r * (NX*NX) + lane*NX + 16*half, offR);
    }
    wsync();
    // ---- pred = P - off @ off^T (into registers) ----
    #pragma unroll
    for (int m = 0; m < 16; ++m) predR[m] = PsR[m];
    #pragma unroll
    for (int k = 0; k < NX; ++k) {
      float fj = offP[k*OPSTRD + pl];              // off[lane][k], conflict-free
      const float4* ov = reinterpret_cast<const float4*>(&offP[k*OPSTRD + 16*half]);
      float4 o0 = ov[0], o1 = ov[1], o2 = ov[2], o3 = ov[3];   // broadcast b128
      predR[0]  -= o0.x*fj; predR[1]  -= o0.y*fj; predR[2]  -= o0.z*fj; predR[3]  -= o0.w*fj;
      predR[4]  -= o1.x*fj; predR[5]  -= o1.y*fj; predR[6]  -= o1.z*fj; predR[7]  -= o1.w*fj;
      predR[8]  -= o2.x*fj; predR[9]  -= o2.y*fj; predR[10] -= o2.z*fj; predR[11] -= o2.w*fj;
      predR[12] -= o3.x*fj; predR[13] -= o3.y*fj; predR[14] -= o3.z*fj; predR[15] -= o3.w*fj;
    }
    wsync();
  }
}

// ---------------- backward: chunked reverse linear scan ----------------
// 256 threads/chunk. Thread owns rows i = grp+8m (grp = t>>5), col j = t&31.
// Staging: thread t loads elements 4t..4t+3 of off[r]/xi[r] (fully coalesced,
// read-once) into regs, deposits to LDS (un-permuting off slots; xi col-major).
// Per-phase column hoists fo[]/fx[] have disjoint live ranges -> no spill.
// vw/bb use stride VSTRD=36 so rows are 16B-aligned -> b128 broadcast reads.
template<typename ST>
__global__ __launch_bounds__(256, 4) void bwd_kernel(
    const ST* __restrict__ offIn, const ST* __restrict__ xIn, const float* __restrict__ uIn,
    const float* __restrict__ epsx, float* __restrict__ outp)
{
  __shared__ float vw[(NM+1)*VSTRD], bb[(NM+1)*VSTRD], off[NX*STRD], xi[NX*STRD];
  const int t = threadIdx.x;
  const int lane = t & 31, grp = t >> 5;
  const int col = t >> 3, sg = t & 7;   // staging column / slot-group
  const int c = blockIdx.x;
  const int r0 = c * CHUNKB, r1 = r0 + CHUNKB;
  int rstart = r1 + WARMB; if (rstart > R_TOT) rstart = R_TOT;
  const bool has64 = (grp == 0);

  for (int e = t; e < (NM+1)*VSTRD; e += 256) vw[e] = 0.f;

  float ov[4], xv[4], gR[9];
  {
    int r = rstart - 1;
    size_t sb = (size_t)r * (NX*NX) + col*NX + 4*sg;
    ld4(ov, offIn + sb);
    ld4(xv, xIn + sb);
    const float* eps_r = epsx + (size_t)r * (NM*NX);
    const float* u_r   = uIn + (size_t)r * NX;
    #pragma unroll
    for (int m = 0; m < 8; ++m) {
      int i = grp + 8*m;
      gR[m] = (i == 0) ? u_r[lane] : eps_r[(i-1)*NX + lane];
    }
    gR[8] = has64 ? eps_r[63*NX + lane] : 0.f;
  }
  __syncthreads();

  for (int r = rstart - 1; r >= r0; --r) {
    float acc[9];
    #pragma unroll
    for (int m = 0; m < 9; ++m) acc[m] = gR[m];
    // ---- deposit this step's off/xi (un-permute off: slot s -> row i) ----
    #pragma unroll
    for (int q = 0; q < 4; ++q) {
      int s = 4*sg + q;
      int io = ((s >> 4) & 1) | ((s & 15) << 1);   // PIDX inverse
      off[io*STRD + col] = ov[q];
      xi[s*STRD + col]   = xv[q];
    }
    __syncthreads();
    // ---- prefetch next (lower) step's inputs ----
    if (r > r0) {
      size_t sb = (size_t)(r-1) * (NX*NX) + col*NX + 4*sg;
      ld4(ov, offIn + sb);
      ld4(xv, xIn + sb);
      const float* eps_n = epsx + (size_t)(r-1) * (NM*NX);
      const float* u_n   = uIn + (size_t)(r-1) * NX;
      #pragma unroll
      for (int m = 0; m < 8; ++m) {
        int i = grp + 8*m;
        gR[m] = (i == 0) ? u_n[lane] : eps_n[(i-1)*NX + lane];
      }
      if (has64) gR[8] = eps_n[63*NX + lane];
    }
    // ---- bb = g - vw @ off : hoist off column into regs, b128 the vw rows ----
    {
      float fo[NX];
      #pragma unroll
      for (int k = 0; k < NX; ++k) fo[k] = off[k*STRD + lane];   // 2-way = free
      #pragma unroll
      for (int m = 0; m < 8; ++m) {
        const float4* vr = reinterpret_cast<const float4*>(&vw[(grp + 8*m)*VSTRD]);
        #pragma unroll
        for (int q = 0; q < 8; ++q) {
          float4 v4 = vr[q];                    // broadcast b128
          acc[m] -= v4.x*fo[4*q] + v4.y*fo[4*q+1] + v4.z*fo[4*q+2] + v4.w*fo[4*q+3];
        }
      }
      if (has64) {
        const float4* vr = reinterpret_cast<const float4*>(&vw[64*VSTRD]);
        #pragma unroll
        for (int q = 0; q < 8; ++q) {
          float4 v4 = vr[q];
          acc[8] -= v4.x*fo[4*q] + v4.y*fo[4*q+1] + v4.z*fo[4*q+2] + v4.w*fo[4*q+3];
        }
      }
    }
    #pragma unroll
    for (int m = 0; m < 8; ++m) bb[(grp + 8*m)*VSTRD + lane] = acc[m];
    if (has64) bb[64*VSTRD + lane] = acc[8];
    __syncthreads();
    // ---- vw = bb @ xi : hoist xi column into regs, b128 the bb rows ----
    float vacc[9];
    #pragma unroll
    for (int m = 0; m < 9; ++m) vacc[m] = 0.f;
    {
      float fx[NX];
      #pragma unroll
      for (int k = 0; k < NX; ++k) fx[k] = xi[k*STRD + lane];    // 2-way = free
      #pragma unroll
      for (int m = 0; m < 8; ++m) {
        const float4* br = reinterpret_cast<const float4*>(&bb[(grp + 8*m)*VSTRD]);
        #pragma unroll
        for (int q = 0; q < 8; ++q) {
          float4 b4 = br[q];                    // broadcast b128
          vacc[m] += b4.x*fx[4*q] + b4.y*fx[4*q+1] + b4.z*fx[4*q+2] + b4.w*fx[4*q+3];
        }
      }
      if (has64) {
        const float4* br = reinterpret_cast<const float4*>(&bb[64*VSTRD]);
        #pragma unroll
        for (int q = 0; q < 8; ++q) {
          float4 b4 = br[q];
          vacc[8] += b4.x*fx[4*q] + b4.y*fx[4*q+1] + b4.z*fx[4*q+2] + b4.w*fx[4*q+3];
        }
      }
    }
    #pragma unroll
    for (int m = 0; m < 8; ++m) vw[(grp + 8*m)*VSTRD + lane] = vacc[m];
    if (has64) vw[64*VSTRD + lane] = vacc[8];
    __syncthreads();
    // ---- out_r[i][j] = vw[i+1][j] + vw[0][j], rows i = grp+8m ----
    if (r < r1) {
      float v0 = vw[lane];
      float* out_r = outp + (size_t)r * (NM*NX);
      #pragma unroll
      for (int m = 0; m < 8; ++m)
        out_r[(grp + 8*m)*NX + lane] = vw[(grp + 8*m + 1)*VSTRD + lane] + v0;
    }
    // no trailing barrier: vw reads here are fenced by next iteration's barriers
    // before any vw write; off/xi deposits are fenced by the post-vw barrier above.
  }
}

extern "C" void kernel_launch(void* const* d_in, const int* in_sizes, int n_in,
                              void* d_out, int out_size, void* d_ws, size_t ws_size,
                              hipStream_t stream) {
  const float* hess  = (const float*)d_in[0];
  const float* grads = (const float*)d_in[1];
  const float* A     = (const float*)d_in[2];
  const float* P     = (const float*)d_in[3];
  const float* initP = (const float*)d_in[4];
  const float* epsx  = (const float*)d_in[5];
  float* outp = (float*)d_out;

  const size_t mats = (size_t)R_TOT * NX * NX;
  const size_t uN   = (size_t)R_TOT * NX;
  const size_t needF32 = 2ull * mats * sizeof(float) + uN * sizeof(float) + 2048 * sizeof(float);

  if (ws_size >= needF32) {
    float* offS  = (float*)d_ws;
    float* xS    = offS + mats;
    float* uS    = xS + mats;
    float* apG   = uS + uN;
    float* apatG = apG + 1024;
    precomp_kernel<<<dim3(1), dim3(64), 0, stream>>>(A, P, apG, apatG);
    fwd_kernel<float><<<dim3(R_TOT/CHUNKF), dim3(64), 0, stream>>>(
        hess, grads, apG, apatG, P, initP, offS, xS, uS);
    bwd_kernel<float><<<dim3(R_TOT/CHUNKB), dim3(256), 0, stream>>>(
        offS, xS, uS, epsx, outp);
  } else {
    __hip_bfloat16* offS = (__hip_bfloat16*)d_ws;
    __hip_bfloat16* xS   = offS + mats;
    float* uS            = (float*)(xS + mats);
    float* apG           = uS + uN;
    float* apatG         = apG + 1024;
    precomp_kernel<<<dim3(1), dim3(64), 0, stream>>>(A, P, apG, apatG);
    fwd_kernel<__hip_bfloat16><<<dim3(R_TOT/CHUNKF), dim3(64), 0, stream>>>(
        hess, grads, apG, apatG, P, initP, offS, xS, uS);
    bwd_kernel<__hip_bfloat16><<<dim3(R_TOT/CHUNKB), dim3(256), 0, stream>>>(
        offS, xS, uS, epsx, outp);
  }
}